// Round 5
// baseline (222.046 us; speedup 1.0000x reference)
//
#include <hip/hip_runtime.h>
#include <hip/hip_bf16.h>

typedef short short8 __attribute__((ext_vector_type(8)));
typedef float floatx4 __attribute__((ext_vector_type(4)));
typedef unsigned uintx4 __attribute__((ext_vector_type(4)));

#define HWSZ 16384   // 128*128
#define WD 128
#define CD 64
#define OD 64
#define XSTR 72      // bf16 LDS row stride (144B = 9 granules): <=2-way banks on b128
#define OSTR 136     // fp32 epilogue stride: <=2-way banks on write/read
#define L2E2 2.8853900817779268f   // 2*log2(e)

__device__ __forceinline__ short f2bf(float f) {
    unsigned u = __builtin_bit_cast(unsigned, f);
    u += 0x7FFFu + ((u >> 16) & 1u);     // RNE
    return (short)(u >> 16);
}

// pack two floats -> packed bf16x2 (RNE; compiler emits v_cvt_pk_bf16_f32)
__device__ __forceinline__ unsigned pack2bf(float a, float b) {
    __hip_bfloat162 h = __float22bfloat162_rn(float2{a, b});
    unsigned u;
    __builtin_memcpy(&u, &h, 4);
    return u;
}

__device__ __forceinline__ float bf2f(short s) {
    return __builtin_bit_cast(float, ((unsigned)(unsigned short)s) << 16);
}

// one-time repack: wgt[o][c][k] fp32 -> wp[k][o][c] bf16, PRE-DOUBLED (folds the
// 2 of 1+tanh = 2*sigmoid(2s) into w; exact in bf16). Coalesced writes.
__global__ void prepack_w(const float* __restrict__ wgt, unsigned short* __restrict__ wp) {
    int idx = blockIdx.x * 256 + threadIdx.x;     // 9*64*64 = 36864
    if (idx < 9 * 64 * 64) {
        int k = idx >> 12, o = (idx >> 6) & 63, c = idx & 63;
        wp[idx] = (unsigned short)f2bf(2.0f * wgt[o * 576 + c * 9 + k]);
    }
}

__global__ __launch_bounds__(256, 4)
void paka_kernel(const float* __restrict__ x, const float* __restrict__ gc,
                 const float* __restrict__ gs, const float* __restrict__ wgt,
                 const unsigned short* __restrict__ wp, float* __restrict__ out)
{
    __shared__ union {
        short xl[130 * XSTR];     // raw x (bf16), slot = w+1, slots 0/129 = zero pad (18.7 KB)
        float o[64 * OSTR];       // epilogue transpose buffer (34.8 KB) -> 4 blocks/CU
    } lds;

    const int tid  = threadIdx.x;
    const int wave = tid >> 6;
    const int lane = tid & 63;

    // XCD swizzle: consecutive ids round-robin across XCDs; give each XCD one
    // batch so the 3x-re-read x rows (4 MB/batch) stay in the local L2.
    const int id  = blockIdx.x;
    const int swz = (id & 7) * 128 + (id >> 3);
    const int b = swz >> 7;             // 8 batches
    const int h = swz & 127;            // 128 rows

    const float* xb  = x  + (size_t)b * CD * HWSZ;
    const float* gcb = gc + (size_t)b * CD * HWSZ;
    const float* gsb = gs + (size_t)b * 9 * HWSZ;

    const int row = lane & 15;
    const int q   = lane >> 4;
    const int mt0 = wave * 2;

    // ---- prefetch eg = exp2(2log2e * gc[c][h][p]) for this lane's MFMA elements
    float eg[2][2][8];
    #pragma unroll
    for (int mt = 0; mt < 2; ++mt) {
        int p = (mt0 + mt) * 16 + row;
        #pragma unroll
        for (int ks = 0; ks < 2; ++ks)
            #pragma unroll
            for (int j = 0; j < 8; ++j) {
                int c = ks * 32 + q * 8 + j;
                eg[mt][ks][j] = __builtin_amdgcn_exp2f(gcb[(size_t)c * HWSZ + h * WD + p] * L2E2);
            }
    }
    // ---- prefetch esv = exp2(2log2e * gs[k][h][p]) for all 9 taps
    float esv[9][2];
    #pragma unroll
    for (int k = 0; k < 9; ++k)
        #pragma unroll
        for (int mt = 0; mt < 2; ++mt) {
            int p = (mt0 + mt) * 16 + row;
            esv[k][mt] = __builtin_amdgcn_exp2f(gsb[k * HWSZ + h * WD + p] * L2E2);
        }

    // zero the two pad rows of xl (w = -1 and w = 128) once
    if (tid < 32)
        *(unsigned*)&lds.xl[0 * XSTR + tid * 2] = 0u;
    else if (tid < 64)
        *(unsigned*)&lds.xl[129 * XSTR + (tid - 32) * 2] = 0u;

    floatx4 acc[2][4];
    #pragma unroll
    for (int i = 0; i < 2; ++i)
        #pragma unroll
        for (int n = 0; n < 4; ++n)
            acc[i][n] = (floatx4){0.f, 0.f, 0.f, 0.f};

    #pragma unroll
    for (int dh = 0; dh < 3; ++dh) {
        const int hh = h + dh - 1;
        if ((unsigned)hh >= 128u) continue;   // block-uniform: taps contribute zero

        __syncthreads();   // previous MFMA phase done reading xl

        // ---- stage x row hh: each thread owns 1 pixel x 8 consecutive channels.
        // Global: scalar loads, lanes 0..31 consecutive p -> 128B segments.
        // LDS: one ds_write_b128/it; granule = 9(p+1)+2g, 9 coprime 32 -> <=2-way.
        {
            const int g = tid >> 5;                  // channel-group 0..7 (c = 8g..8g+7)
            const float* xg = xb + (size_t)(8 * g) * HWSZ + hh * WD;
            #pragma unroll
            for (int it = 0; it < 4; ++it) {
                int p = it * 32 + (tid & 31);
                uintx4 pv;
                #pragma unroll
                for (int cc = 0; cc < 4; ++cc) {
                    float a  = xg[(size_t)(2 * cc) * HWSZ + p];
                    float b2 = xg[(size_t)(2 * cc + 1) * HWSZ + p];
                    pv[cc] = pack2bf(a, b2);
                }
                *(uintx4*)&lds.xl[(p + 1) * XSTR + g * 8] = pv;
            }
        }

        __syncthreads();

        // ---- 3 taps share this staging; W fragments straight from global wp
        // (73.7 KB table, L2-hot, shared by all blocks): no wl LDS, no W stage.
        #pragma unroll
        for (int dw = 0; dw < 3; ++dw) {
            const int k = dh * 3 + dw;
            #pragma unroll
            for (int ks = 0; ks < 2; ++ks) {
                short8 bv[4];
                if (wp) {
                    const unsigned short* wk = wp + k * 4096 + ks * 32 + q * 8;
                    #pragma unroll
                    for (int nt = 0; nt < 4; ++nt)
                        bv[nt] = *(const short8*)&wk[(nt * 16 + row) * 64];
                } else {
                    #pragma unroll
                    for (int nt = 0; nt < 4; ++nt)
                        #pragma unroll
                        for (int j = 0; j < 8; ++j) {
                            int o = nt * 16 + row, c = ks * 32 + q * 8 + j;
                            bv[nt][j] = f2bf(2.0f * wgt[o * 576 + c * 9 + k]);
                        }
                }

                short8 af[2];
                #pragma unroll
                for (int mt = 0; mt < 2; ++mt) {
                    int wslot = (mt0 + mt) * 16 + row + dw;   // = p + dw, xl slot of w=p+dw-1
                    short8 raw = *(const short8*)&lds.xl[wslot * XSTR + ks * 32 + q * 8];
                    float es = esv[k][mt];
                    #pragma unroll
                    for (int jj = 0; jj < 4; ++jj) {
                        float d0 = fmaf(eg[mt][ks][2 * jj],     es, 1.0f);
                        float d1 = fmaf(eg[mt][ks][2 * jj + 1], es, 1.0f);
                        float r0 = __builtin_amdgcn_rcpf(d0);
                        float r1 = __builtin_amdgcn_rcpf(d1);
                        float x0 = bf2f(raw[2 * jj]);
                        float x1 = bf2f(raw[2 * jj + 1]);
                        float t0 = fmaf(-x0, r0, x0);   // x * u/(1+u); the 2 lives in w
                        float t1 = fmaf(-x1, r1, x1);
                        ((unsigned*)&af[mt])[jj] = pack2bf(t0, t1);
                    }
                }
                #pragma unroll
                for (int nt = 0; nt < 4; ++nt) {
                    acc[0][nt] = __builtin_amdgcn_mfma_f32_16x16x32_bf16(af[0], bv[nt], acc[0][nt], 0, 0, 0);
                    acc[1][nt] = __builtin_amdgcn_mfma_f32_16x16x32_bf16(af[1], bv[nt], acc[1][nt], 0, 0, 0);
                }
            }
        }
    }

    __syncthreads();

    // D layout: col(=o) = lane&15, rowD(=p) = (lane>>4)*4 + reg.
    // Vector b128 transpose writes: granule = 2*row + q (mod 32) -> <=2-way = free.
    #pragma unroll
    for (int i = 0; i < 2; ++i) {
        int prow = (mt0 + i) * 16 + q * 4;
        #pragma unroll
        for (int nt = 0; nt < 4; ++nt) {
            int o = nt * 16 + row;
            *(floatx4*)&lds.o[o * OSTR + prow] = acc[i][nt];
        }
    }

    __syncthreads();

    // coalesced float4 stores: out[b][o][h][0..127]; read granule = 2o+j -> 2-way = free
    float* outb = out + ((size_t)b * OD) * HWSZ + h * WD;
    #pragma unroll
    for (int it = 0; it < 8; ++it) {
        int idx = it * 256 + tid;              // 2048 float4s
        int o = idx >> 5, p4 = (idx & 31) * 4;
        *(floatx4*)&outb[(size_t)o * HWSZ + p4] = *(const floatx4*)&lds.o[o * OSTR + p4];
    }
}

extern "C" void kernel_launch(void* const* d_in, const int* in_sizes, int n_in,
                              void* d_out, int out_size, void* d_ws, size_t ws_size,
                              hipStream_t stream) {
    const float* x   = (const float*)d_in[0];
    const float* gcp = (const float*)d_in[1];
    const float* gsp = (const float*)d_in[2];
    const float* wgt = (const float*)d_in[3];
    float* out = (float*)d_out;

    const bool use_wp = ws_size >= (size_t)(9 * 64 * 64 * sizeof(unsigned short));
    unsigned short* wp = use_wp ? (unsigned short*)d_ws : nullptr;
    if (use_wp)
        prepack_w<<<dim3(144), dim3(256), 0, stream>>>(wgt, wp);
    paka_kernel<<<dim3(1024), dim3(256), 0, stream>>>(x, gcp, gsp, wgt, wp, out);
}

// Round 6
// 183.770 us; speedup vs baseline: 1.2083x; 1.2083x over previous
//
#include <hip/hip_runtime.h>
#include <hip/hip_bf16.h>

typedef short short8 __attribute__((ext_vector_type(8)));
typedef float floatx4 __attribute__((ext_vector_type(4)));
typedef unsigned uintx4 __attribute__((ext_vector_type(4)));

#define HWSZ 16384   // 128*128
#define WD 128
#define CD 64
#define OD 64
#define XSTR 72      // bf16 LDS row stride (144B = 9 granules): <=2-way banks on b128
#define OSTR2 68     // fp32 epilogue stride (half row): <=2-way write, <=3-way read
#define L2E2 2.8853900817779268f   // 2*log2(e)

__device__ __forceinline__ short f2bf(float f) {
    unsigned u = __builtin_bit_cast(unsigned, f);
    u += 0x7FFFu + ((u >> 16) & 1u);     // RNE
    return (short)(u >> 16);
}

// pack two floats -> packed bf16x2 (RNE; compiler emits v_cvt_pk_bf16_f32)
__device__ __forceinline__ unsigned pack2bf(float a, float b) {
    __hip_bfloat162 h = __float22bfloat162_rn(float2{a, b});
    unsigned u;
    __builtin_memcpy(&u, &h, 4);
    return u;
}

__device__ __forceinline__ float bf2f(short s) {
    return __builtin_bit_cast(float, ((unsigned)(unsigned short)s) << 16);
}

// one-time repack: wgt[o][c][k] fp32 -> wp[k][o][c] bf16, PRE-DOUBLED (folds the
// 2 of 1+tanh = 2*sigmoid(2s) into w; exact in bf16). Coalesced writes.
__global__ void prepack_w(const float* __restrict__ wgt, unsigned short* __restrict__ wp) {
    int idx = blockIdx.x * 256 + threadIdx.x;     // 9*64*64 = 36864
    if (idx < 9 * 64 * 64) {
        int k = idx >> 12, o = (idx >> 6) & 63, c = idx & 63;
        wp[idx] = (unsigned short)f2bf(2.0f * wgt[o * 576 + c * 9 + k]);
    }
}

__global__ __launch_bounds__(256, 3)
void paka_kernel(const float* __restrict__ x, const float* __restrict__ gc,
                 const float* __restrict__ gs, const float* __restrict__ wgt,
                 const unsigned short* __restrict__ wp, float* __restrict__ out)
{
    // Half-row block: 64 pixels. LDS = max(9.5, 17.4) KB -> 9 blocks/CU by LDS.
    __shared__ union {
        short xl[66 * XSTR];      // x half-row bf16; slot s = w - p0 + 1, s=0/65 halo
        float o[64 * OSTR2];      // epilogue transpose buffer (17.4 KB)
    } lds;

    const int tid  = threadIdx.x;
    const int wave = tid >> 6;
    const int lane = tid & 63;

    // XCD swizzle: id%8 -> XCD; each XCD owns one batch (x+gc rows L2-local),
    // consecutive blocks on an XCD = adjacent (h, half) -> halo/row reuse in L2.
    const int id  = blockIdx.x;               // 0..2047
    const int swz = (id & 7) * 256 + (id >> 3);
    const int b   = swz >> 8;                 // batch 0..7
    const int hph = swz & 255;
    const int h   = hph >> 1;                 // row 0..127
    const int p0  = (hph & 1) * 64;           // half-row origin

    const float* xb  = x  + (size_t)b * CD * HWSZ;
    const float* gcb = gc + (size_t)b * CD * HWSZ;
    const float* gsb = gs + (size_t)b * 9 * HWSZ;

    const int row = lane & 15;
    const int q   = lane >> 4;
    const int pl  = wave * 16 + row;          // local pixel 0..63 (MFMA A-row)
    const int pg  = p0 + pl;                  // global pixel

    // ---- prefetch eg = exp2(2log2e * gc[c][h][pg]) for this lane's MFMA elements
    float eg[2][8];
    #pragma unroll
    for (int ks = 0; ks < 2; ++ks)
        #pragma unroll
        for (int j = 0; j < 8; ++j) {
            int c = ks * 32 + q * 8 + j;
            eg[ks][j] = __builtin_amdgcn_exp2f(gcb[(size_t)c * HWSZ + h * WD + pg] * L2E2);
        }
    // ---- prefetch esv = exp2(2log2e * gs[k][h][pg]) for all 9 taps
    float esv[9];
    #pragma unroll
    for (int k = 0; k < 9; ++k)
        esv[k] = __builtin_amdgcn_exp2f(gsb[k * HWSZ + h * WD + pg] * L2E2);

    floatx4 acc[4];
    #pragma unroll
    for (int n = 0; n < 4; ++n)
        acc[n] = (floatx4){0.f, 0.f, 0.f, 0.f};

    #pragma unroll
    for (int dh = 0; dh < 3; ++dh) {
        const int hh = h + dh - 1;
        if ((unsigned)hh >= 128u) continue;   // block-uniform: taps contribute zero

        __syncthreads();   // previous MFMA phase done reading xl

        // ---- halo columns: slot 0 (w=p0-1) and slot 65 (w=p0+64); zero if OOB
        if (tid < 64) {
            int side = tid >> 5, cp = tid & 31;
            int w = p0 - 1 + side * 65;
            unsigned v = 0u;
            if ((unsigned)w < 128u) {
                const float* xc = xb + (size_t)(2 * cp) * HWSZ + hh * WD + w;
                v = pack2bf(xc[0], xc[HWSZ]);
            }
            *(unsigned*)&lds.xl[side * 65 * XSTR + 2 * cp] = v;
        }
        // ---- main 64 columns: thread owns 1 px x 8 consecutive channels.
        // Global: 32-lane-consecutive p -> 128B segments. LDS: ds_write_b128,
        // granule = 9*slot + g (9 coprime 32) -> 2-way = free.
        {
            const int g = tid >> 5;
            const float* xg = xb + (size_t)(8 * g) * HWSZ + hh * WD + p0;
            #pragma unroll
            for (int it = 0; it < 2; ++it) {
                int plx = it * 32 + (tid & 31);
                uintx4 pv;
                #pragma unroll
                for (int cc = 0; cc < 4; ++cc)
                    pv[cc] = pack2bf(xg[(size_t)(2 * cc) * HWSZ + plx],
                                     xg[(size_t)(2 * cc + 1) * HWSZ + plx]);
                *(uintx4*)&lds.xl[(plx + 1) * XSTR + g * 8] = pv;
            }
        }

        __syncthreads();

        // ---- 3 dw taps share this staging; W fragments straight from global wp
        // (per-dh slice 24.6 KB, L1-resident; table shared by all 2048 blocks).
        #pragma unroll
        for (int dw = 0; dw < 3; ++dw) {
            const int k = dh * 3 + dw;
            const float es = esv[k];
            #pragma unroll
            for (int ks = 0; ks < 2; ++ks) {
                short8 bv[4];
                if (wp) {
                    const unsigned short* wk = wp + k * 4096 + ks * 32 + q * 8;
                    #pragma unroll
                    for (int nt = 0; nt < 4; ++nt)
                        bv[nt] = *(const short8*)&wk[(nt * 16 + row) * 64];
                } else {
                    #pragma unroll
                    for (int nt = 0; nt < 4; ++nt)
                        #pragma unroll
                        for (int j = 0; j < 8; ++j) {
                            int o = nt * 16 + row, c = ks * 32 + q * 8 + j;
                            bv[nt][j] = f2bf(2.0f * wgt[o * 576 + c * 9 + k]);
                        }
                }

                // slot = pl + dw holds w = pg + dw - 1
                short8 raw = *(const short8*)&lds.xl[(pl + dw) * XSTR + ks * 32 + q * 8];
                short8 af;
                #pragma unroll
                for (int jj = 0; jj < 4; ++jj) {
                    float d0 = fmaf(eg[ks][2 * jj],     es, 1.0f);
                    float d1 = fmaf(eg[ks][2 * jj + 1], es, 1.0f);
                    float r0 = __builtin_amdgcn_rcpf(d0);
                    float r1 = __builtin_amdgcn_rcpf(d1);
                    float x0 = bf2f(raw[2 * jj]);
                    float x1 = bf2f(raw[2 * jj + 1]);
                    float t0 = fmaf(-x0, r0, x0);   // x * u/(1+u); the 2 lives in w
                    float t1 = fmaf(-x1, r1, x1);
                    ((unsigned*)&af)[jj] = pack2bf(t0, t1);
                }
                #pragma unroll
                for (int nt = 0; nt < 4; ++nt)
                    acc[nt] = __builtin_amdgcn_mfma_f32_16x16x32_bf16(af, bv[nt], acc[nt], 0, 0, 0);
            }
        }
    }

    __syncthreads();

    // D layout: col(=o-local) = lane&15, rowD(=p-local) = q*4 + reg.
    // b128 transpose writes: granule = 17*row + q + const -> 2-way = free.
    {
        int prow = wave * 16 + q * 4;
        #pragma unroll
        for (int nt = 0; nt < 4; ++nt) {
            int o = nt * 16 + row;
            *(floatx4*)&lds.o[o * OSTR2 + prow] = acc[nt];
        }
    }

    __syncthreads();

    // coalesced float4 stores: out[b][o][h][p0..p0+63] (256B per o-group)
    float* outb = out + ((size_t)b * OD) * HWSZ + h * WD + p0;
    #pragma unroll
    for (int it = 0; it < 4; ++it) {
        int idx = it * 256 + tid;              // 1024 float4s
        int o = idx >> 4, p4 = (idx & 15) * 4;
        *(floatx4*)&outb[(size_t)o * HWSZ + p4] = *(const floatx4*)&lds.o[o * OSTR2 + p4];
    }
}

extern "C" void kernel_launch(void* const* d_in, const int* in_sizes, int n_in,
                              void* d_out, int out_size, void* d_ws, size_t ws_size,
                              hipStream_t stream) {
    const float* x   = (const float*)d_in[0];
    const float* gcp = (const float*)d_in[1];
    const float* gsp = (const float*)d_in[2];
    const float* wgt = (const float*)d_in[3];
    float* out = (float*)d_out;

    const bool use_wp = ws_size >= (size_t)(9 * 64 * 64 * sizeof(unsigned short));
    unsigned short* wp = use_wp ? (unsigned short*)d_ws : nullptr;
    if (use_wp)
        prepack_w<<<dim3(144), dim3(256), 0, stream>>>(wgt, wp);
    paka_kernel<<<dim3(2048), dim3(256), 0, stream>>>(x, gcp, gsp, wgt, wp, out);
}

// Round 7
// 164.025 us; speedup vs baseline: 1.3537x; 1.1204x over previous
//
#include <hip/hip_runtime.h>
#include <hip/hip_bf16.h>

typedef short short8 __attribute__((ext_vector_type(8)));
typedef float floatx4 __attribute__((ext_vector_type(4)));
typedef unsigned uintx4 __attribute__((ext_vector_type(4)));

#define HWSZ 16384   // 128*128
#define WD 128
#define CD 64
#define OD 64
#define XSTR 72      // bf16 LDS row stride (144B = 9 granules): <=2-way banks on b128
#define OSTR 136     // fp32 epilogue stride: <=2-way banks on write/read
#define L2E2 2.8853900817779268f   // 2*log2(e)

__device__ __forceinline__ short f2bf(float f) {
    unsigned u = __builtin_bit_cast(unsigned, f);
    u += 0x7FFFu + ((u >> 16) & 1u);     // RNE
    return (short)(u >> 16);
}

// pack two floats -> packed bf16x2 (RNE; compiler emits v_cvt_pk_bf16_f32)
__device__ __forceinline__ unsigned pack2bf(float a, float b) {
    __hip_bfloat162 h = __float22bfloat162_rn(float2{a, b});
    unsigned u;
    __builtin_memcpy(&u, &h, 4);
    return u;
}

__device__ __forceinline__ float bf2f(short s) {
    return __builtin_bit_cast(float, ((unsigned)(unsigned short)s) << 16);
}

// one-time repack: wgt[o][c][k] fp32 -> wp[k][o][c] bf16, PRE-DOUBLED (folds the
// 2 of 1+tanh = 2*sigmoid(2s) into w; exact in bf16). Coalesced writes.
__global__ void prepack_w(const float* __restrict__ wgt, unsigned short* __restrict__ wp) {
    int idx = blockIdx.x * 256 + threadIdx.x;     // 9*64*64 = 36864
    if (idx < 9 * 64 * 64) {
        int k = idx >> 12, o = (idx >> 6) & 63, c = idx & 63;
        wp[idx] = (unsigned short)f2bf(2.0f * wgt[o * 576 + c * 9 + k]);
    }
}

// raw loads for one x row: 16 float2 (8 channels x 4 pixel-quads), named regs only
#define RAWLOAD(hh, zero)                                                     \
    do {                                                                      \
        if (!(zero)) {                                                        \
            const float* xg_ = xb + (size_t)(8 * g) * HWSZ + (size_t)(hh) * WD; \
            int p_ = (tid & 31);                                              \
            f0 = float2{xg_[0*HWSZ + p_],      xg_[1*HWSZ + p_]};             \
            f1 = float2{xg_[2*HWSZ + p_],      xg_[3*HWSZ + p_]};             \
            f2 = float2{xg_[4*HWSZ + p_],      xg_[5*HWSZ + p_]};             \
            f3 = float2{xg_[6*HWSZ + p_],      xg_[7*HWSZ + p_]};             \
            f4 = float2{xg_[0*HWSZ + p_ + 32], xg_[1*HWSZ + p_ + 32]};        \
            f5 = float2{xg_[2*HWSZ + p_ + 32], xg_[3*HWSZ + p_ + 32]};        \
            f6 = float2{xg_[4*HWSZ + p_ + 32], xg_[5*HWSZ + p_ + 32]};        \
            f7 = float2{xg_[6*HWSZ + p_ + 32], xg_[7*HWSZ + p_ + 32]};        \
            f8 = float2{xg_[0*HWSZ + p_ + 64], xg_[1*HWSZ + p_ + 64]};        \
            f9 = float2{xg_[2*HWSZ + p_ + 64], xg_[3*HWSZ + p_ + 64]};        \
            fa = float2{xg_[4*HWSZ + p_ + 64], xg_[5*HWSZ + p_ + 64]};        \
            fb = float2{xg_[6*HWSZ + p_ + 64], xg_[7*HWSZ + p_ + 64]};        \
            fc = float2{xg_[0*HWSZ + p_ + 96], xg_[1*HWSZ + p_ + 96]};        \
            fd = float2{xg_[2*HWSZ + p_ + 96], xg_[3*HWSZ + p_ + 96]};        \
            fe = float2{xg_[4*HWSZ + p_ + 96], xg_[5*HWSZ + p_ + 96]};        \
            ff = float2{xg_[6*HWSZ + p_ + 96], xg_[7*HWSZ + p_ + 96]};        \
        } else {                                                              \
            f0=f1=f2=f3=f4=f5=f6=f7=f8=f9=fa=fb=fc=fd=fe=ff=float2{0.f,0.f};  \
        }                                                                     \
    } while (0)

#define PACKROW()                                                             \
    do {                                                                      \
        A0 = (uintx4){pack2bf(f0.x,f0.y), pack2bf(f1.x,f1.y),                 \
                      pack2bf(f2.x,f2.y), pack2bf(f3.x,f3.y)};                \
        A1 = (uintx4){pack2bf(f4.x,f4.y), pack2bf(f5.x,f5.y),                 \
                      pack2bf(f6.x,f6.y), pack2bf(f7.x,f7.y)};                \
        A2 = (uintx4){pack2bf(f8.x,f8.y), pack2bf(f9.x,f9.y),                 \
                      pack2bf(fa.x,fa.y), pack2bf(fb.x,fb.y)};                \
        A3 = (uintx4){pack2bf(fc.x,fc.y), pack2bf(fd.x,fd.y),                 \
                      pack2bf(fe.x,fe.y), pack2bf(ff.x,ff.y)};                \
    } while (0)

#define STOREROW(buf)                                                         \
    do {                                                                      \
        short* b_ = (buf);                                                    \
        int p_ = (tid & 31);                                                  \
        *(uintx4*)&b_[(p_ +  1) * XSTR + g * 8] = A0;                         \
        *(uintx4*)&b_[(p_ + 33) * XSTR + g * 8] = A1;                         \
        *(uintx4*)&b_[(p_ + 65) * XSTR + g * 8] = A2;                         \
        *(uintx4*)&b_[(p_ + 97) * XSTR + g * 8] = A3;                         \
    } while (0)

__global__ __launch_bounds__(256, 3)
void paka_kernel(const float* __restrict__ x, const float* __restrict__ gc,
                 const float* __restrict__ gs, const float* __restrict__ wgt,
                 const unsigned short* __restrict__ wp, float* __restrict__ out)
{
    __shared__ union {
        short xb2[2][130 * XSTR];   // double-buffered x rows (37.4 KB)
        float o[64 * OSTR];         // epilogue transpose buffer (34.8 KB)
    } lds;

    const int tid  = threadIdx.x;
    const int wave = tid >> 6;
    const int lane = tid & 63;

    // XCD swizzle: id%8 -> XCD; one batch per XCD -> x/gc rows L2-local (proven
    // FETCH reduction in R4/R6).
    const int id  = blockIdx.x;
    const int swz = (id & 7) * 128 + (id >> 3);
    const int b = swz >> 7;             // 8 batches
    const int h = swz & 127;            // 128 rows

    const float* xb  = x  + (size_t)b * CD * HWSZ;
    const float* gcb = gc + (size_t)b * CD * HWSZ;
    const float* gsb = gs + (size_t)b * 9 * HWSZ;

    const int row = lane & 15;
    const int q   = lane >> 4;
    const int mt0 = wave * 2;
    const int g   = tid >> 5;           // channel-group for staging

    // ---- prefetch eg = exp2(2log2e * gc[c][h][p]) for this lane's MFMA elements
    float eg[2][2][8];
    #pragma unroll
    for (int mt = 0; mt < 2; ++mt) {
        int p = (mt0 + mt) * 16 + row;
        #pragma unroll
        for (int ks = 0; ks < 2; ++ks)
            #pragma unroll
            for (int j = 0; j < 8; ++j) {
                int c = ks * 32 + q * 8 + j;
                eg[mt][ks][j] = __builtin_amdgcn_exp2f(gcb[(size_t)c * HWSZ + h * WD + p] * L2E2);
            }
    }
    // ---- prefetch esv = exp2(2log2e * gs[k][h][p]) for all 9 taps
    float esv[9][2];
    #pragma unroll
    for (int k = 0; k < 9; ++k)
        #pragma unroll
        for (int mt = 0; mt < 2; ++mt) {
            int p = (mt0 + mt) * 16 + row;
            esv[k][mt] = __builtin_amdgcn_exp2f(gsb[k * HWSZ + h * WD + p] * L2E2);
        }

    // zero the pad rows (w=-1 and w=128) of both buffers once
    if (tid < 32) {
        *(unsigned*)&lds.xb2[0][0 * XSTR + tid * 2] = 0u;
        *(unsigned*)&lds.xb2[1][0 * XSTR + tid * 2] = 0u;
    } else if (tid < 64) {
        int t = tid - 32;
        *(unsigned*)&lds.xb2[0][129 * XSTR + t * 2] = 0u;
        *(unsigned*)&lds.xb2[1][129 * XSTR + t * 2] = 0u;
    }

    floatx4 acc[2][4];
    #pragma unroll
    for (int i = 0; i < 2; ++i)
        #pragma unroll
        for (int n = 0; n < 4; ++n)
            acc[i][n] = (floatx4){0.f, 0.f, 0.f, 0.f};

    // ---- pipeline state: all named registers (no arrays across barriers)
    float2 f0,f1,f2,f3,f4,f5,f6,f7,f8,f9,fa,fb,fc,fd,fe,ff;
    uintx4 A0, A1, A2, A3;

    RAWLOAD(h - 1, h == 0);  PACKROW();  STOREROW(lds.xb2[0]);   // row h-1 -> buf0
    RAWLOAD(h, false);       PACKROW();                           // row h packed, held
    __syncthreads();                                              // buf0 ready

    #pragma unroll
    for (int dh = 0; dh < 3; ++dh) {
        // stage the held row into the other buffer; then issue next row's loads
        if (dh < 2)
            STOREROW(lds.xb2[(dh + 1) & 1]);
        if (dh == 0)
            RAWLOAD(h + 1, h == 127);     // loads in flight under dh0 compute

        const short* cur = lds.xb2[dh & 1];

        #pragma unroll
        for (int dw = 0; dw < 3; ++dw) {
            const int k = dh * 3 + dw;
            #pragma unroll
            for (int ks = 0; ks < 2; ++ks) {
                // W fragments straight from global wp (73.7 KB, L2-hot)
                short8 bv0, bv1, bv2, bv3;
                if (wp) {
                    const unsigned short* wk = wp + k * 4096 + ks * 32 + q * 8;
                    bv0 = *(const short8*)&wk[(0 * 16 + row) * 64];
                    bv1 = *(const short8*)&wk[(1 * 16 + row) * 64];
                    bv2 = *(const short8*)&wk[(2 * 16 + row) * 64];
                    bv3 = *(const short8*)&wk[(3 * 16 + row) * 64];
                } else {
                    #pragma unroll
                    for (int j = 0; j < 8; ++j) {
                        int c = ks * 32 + q * 8 + j;
                        bv0[j] = f2bf(2.0f * wgt[(0*16+row) * 576 + c * 9 + k]);
                        bv1[j] = f2bf(2.0f * wgt[(1*16+row) * 576 + c * 9 + k]);
                        bv2[j] = f2bf(2.0f * wgt[(2*16+row) * 576 + c * 9 + k]);
                        bv3[j] = f2bf(2.0f * wgt[(3*16+row) * 576 + c * 9 + k]);
                    }
                }

                short8 af[2];
                #pragma unroll
                for (int mt = 0; mt < 2; ++mt) {
                    int wslot = (mt0 + mt) * 16 + row + dw;   // xl slot of w = p+dw-1
                    short8 raw = *(const short8*)&cur[wslot * XSTR + ks * 32 + q * 8];
                    float es = esv[k][mt];
                    #pragma unroll
                    for (int jj = 0; jj < 4; ++jj) {
                        float d0 = fmaf(eg[mt][ks][2 * jj],     es, 1.0f);
                        float d1 = fmaf(eg[mt][ks][2 * jj + 1], es, 1.0f);
                        float r0 = __builtin_amdgcn_rcpf(d0);
                        float r1 = __builtin_amdgcn_rcpf(d1);
                        float x0 = bf2f(raw[2 * jj]);
                        float x1 = bf2f(raw[2 * jj + 1]);
                        float t0 = fmaf(-x0, r0, x0);   // x * u/(1+u); the 2 lives in w
                        float t1 = fmaf(-x1, r1, x1);
                        ((unsigned*)&af[mt])[jj] = pack2bf(t0, t1);
                    }
                }
                acc[0][0] = __builtin_amdgcn_mfma_f32_16x16x32_bf16(af[0], bv0, acc[0][0], 0, 0, 0);
                acc[1][0] = __builtin_amdgcn_mfma_f32_16x16x32_bf16(af[1], bv0, acc[1][0], 0, 0, 0);
                acc[0][1] = __builtin_amdgcn_mfma_f32_16x16x32_bf16(af[0], bv1, acc[0][1], 0, 0, 0);
                acc[1][1] = __builtin_amdgcn_mfma_f32_16x16x32_bf16(af[1], bv1, acc[1][1], 0, 0, 0);
                acc[0][2] = __builtin_amdgcn_mfma_f32_16x16x32_bf16(af[0], bv2, acc[0][2], 0, 0, 0);
                acc[1][2] = __builtin_amdgcn_mfma_f32_16x16x32_bf16(af[1], bv2, acc[1][2], 0, 0, 0);
                acc[0][3] = __builtin_amdgcn_mfma_f32_16x16x32_bf16(af[0], bv3, acc[0][3], 0, 0, 0);
                acc[1][3] = __builtin_amdgcn_mfma_f32_16x16x32_bf16(af[1], bv3, acc[1][3], 0, 0, 0);
            }
        }
        if (dh == 0)
            PACKROW();                    // loads have had the whole dh0 compute to land
        __syncthreads();                  // staged buffer visible; cur free for reuse
    }

    // D layout: col(=o) = lane&15, rowD(=p) = (lane>>4)*4 + reg.
    // b128 transpose writes: granule = 2*row + q (mod 32) -> <=2-way = free.
    #pragma unroll
    for (int i = 0; i < 2; ++i) {
        int prow = (mt0 + i) * 16 + q * 4;
        #pragma unroll
        for (int nt = 0; nt < 4; ++nt) {
            int o = nt * 16 + row;
            *(floatx4*)&lds.o[o * OSTR + prow] = acc[i][nt];
        }
    }

    __syncthreads();

    // coalesced float4 stores: out[b][o][h][0..127]; read granule 2o+j -> 2-way = free
    float* outb = out + ((size_t)b * OD) * HWSZ + h * WD;
    #pragma unroll
    for (int it = 0; it < 8; ++it) {
        int idx = it * 256 + tid;              // 2048 float4s
        int o = idx >> 5, p4 = (idx & 31) * 4;
        *(floatx4*)&outb[(size_t)o * HWSZ + p4] = *(const floatx4*)&lds.o[o * OSTR + p4];
    }
}

extern "C" void kernel_launch(void* const* d_in, const int* in_sizes, int n_in,
                              void* d_out, int out_size, void* d_ws, size_t ws_size,
                              hipStream_t stream) {
    const float* x   = (const float*)d_in[0];
    const float* gcp = (const float*)d_in[1];
    const float* gsp = (const float*)d_in[2];
    const float* wgt = (const float*)d_in[3];
    float* out = (float*)d_out;

    const bool use_wp = ws_size >= (size_t)(9 * 64 * 64 * sizeof(unsigned short));
    unsigned short* wp = use_wp ? (unsigned short*)d_ws : nullptr;
    if (use_wp)
        prepack_w<<<dim3(144), dim3(256), 0, stream>>>(wgt, wp);
    paka_kernel<<<dim3(1024), dim3(256), 0, stream>>>(x, gcp, gsp, wgt, wp, out);
}

// Round 8
// 148.280 us; speedup vs baseline: 1.4975x; 1.1062x over previous
//
#include <hip/hip_runtime.h>
#include <hip/hip_bf16.h>

typedef short short8 __attribute__((ext_vector_type(8)));
typedef float floatx4 __attribute__((ext_vector_type(4)));
typedef unsigned uintx4 __attribute__((ext_vector_type(4)));

#define HWSZ 16384   // 128*128
#define WD 128
#define CD 64
#define OD 64
#define XSTR 72      // bf16 LDS row stride (144B = 9 granules): <=2-way banks on b128
#define OSTR 136     // fp32 epilogue stride: <=2-way banks on write/read
#define L2E2 2.8853900817779268f   // 2*log2(e)

__device__ __forceinline__ short f2bf(float f) {
    unsigned u = __builtin_bit_cast(unsigned, f);
    u += 0x7FFFu + ((u >> 16) & 1u);     // RNE
    return (short)(u >> 16);
}

// pack two floats -> packed bf16x2 (RNE; compiler emits v_cvt_pk_bf16_f32)
__device__ __forceinline__ unsigned pack2bf(float a, float b) {
    __hip_bfloat162 h = __float22bfloat162_rn(float2{a, b});
    unsigned u;
    __builtin_memcpy(&u, &h, 4);
    return u;
}

__device__ __forceinline__ float bf2f(short s) {
    return __builtin_bit_cast(float, ((unsigned)(unsigned short)s) << 16);
}

// one-time repack: wgt[o][c][k] fp32 -> wp[k][o][c] bf16, PRE-DOUBLED (folds the
// 2 of 1+tanh = 2*sigmoid(2s) into w; exact in bf16). Coalesced writes.
__global__ void prepack_w(const float* __restrict__ wgt, unsigned short* __restrict__ wp) {
    int idx = blockIdx.x * 256 + threadIdx.x;     // 9*64*64 = 36864
    if (idx < 9 * 64 * 64) {
        int k = idx >> 12, o = (idx >> 6) & 63, c = idx & 63;
        wp[idx] = (unsigned short)f2bf(2.0f * wgt[o * 576 + c * 9 + k]);
    }
}

__global__ __launch_bounds__(256, 3)
void paka_kernel(const float* __restrict__ x, const float* __restrict__ gc,
                 const float* __restrict__ gs, const float* __restrict__ wgt,
                 const unsigned short* __restrict__ wp, float* __restrict__ out)
{
    __shared__ union {
        short xl[130 * XSTR];     // raw x (bf16), slot = w+1, slots 0/129 = zero pad (18.7 KB)
        float o[64 * OSTR];       // epilogue transpose buffer (34.8 KB)
    } lds;

    const int tid  = threadIdx.x;
    const int wave = tid >> 6;
    const int lane = tid & 63;

    // XCD swizzle (proven: FETCH 68->~44 MB): id%8 -> XCD; one batch per XCD so
    // the 3x-re-read x rows + gc rows stay in the local 4 MB L2.
    const int id  = blockIdx.x;
    const int swz = (id & 7) * 128 + (id >> 3);
    const int b = swz >> 7;             // 8 batches
    const int h = swz & 127;            // 128 rows

    const float* xb  = x  + (size_t)b * CD * HWSZ;
    const float* gcb = gc + (size_t)b * CD * HWSZ;
    const float* gsb = gs + (size_t)b * 9 * HWSZ;

    const int row = lane & 15;
    const int q   = lane >> 4;
    const int mt0 = wave * 2;

    // ---- prefetch eg = exp2(2log2e * gc[c][h][p]) for this lane's MFMA elements
    float eg[2][2][8];
    #pragma unroll
    for (int mt = 0; mt < 2; ++mt) {
        int p = (mt0 + mt) * 16 + row;
        #pragma unroll
        for (int ks = 0; ks < 2; ++ks)
            #pragma unroll
            for (int j = 0; j < 8; ++j) {
                int c = ks * 32 + q * 8 + j;
                eg[mt][ks][j] = __builtin_amdgcn_exp2f(gcb[(size_t)c * HWSZ + h * WD + p] * L2E2);
            }
    }
    // ---- prefetch esv = exp2(2log2e * gs[k][h][p]) for all 9 taps
    float esv[9][2];
    #pragma unroll
    for (int k = 0; k < 9; ++k)
        #pragma unroll
        for (int mt = 0; mt < 2; ++mt) {
            int p = (mt0 + mt) * 16 + row;
            esv[k][mt] = __builtin_amdgcn_exp2f(gsb[k * HWSZ + h * WD + p] * L2E2);
        }

    // zero the two pad rows of xl (w = -1 and w = 128) once
    if (tid < 32)
        *(unsigned*)&lds.xl[0 * XSTR + tid * 2] = 0u;
    else if (tid < 64)
        *(unsigned*)&lds.xl[129 * XSTR + (tid - 32) * 2] = 0u;

    floatx4 acc[2][4];
    #pragma unroll
    for (int i = 0; i < 2; ++i)
        #pragma unroll
        for (int n = 0; n < 4; ++n)
            acc[i][n] = (floatx4){0.f, 0.f, 0.f, 0.f};

    #pragma unroll
    for (int dh = 0; dh < 3; ++dh) {
        const int hh = h + dh - 1;
        if ((unsigned)hh >= 128u) continue;   // block-uniform: taps contribute zero

        __syncthreads();   // previous MFMA phase done reading xl

        // ---- stage x row hh: each thread owns 1 pixel x 8 consecutive channels.
        // Global: scalar loads, lanes 0..31 consecutive p -> 128B segments.
        // LDS: ds_write_b128; granule = 9(p+1)+g (9 coprime 32) -> <=2-way = free.
        {
            const int g = tid >> 5;                  // channel-group 0..7 (c = 8g..8g+7)
            const float* xg = xb + (size_t)(8 * g) * HWSZ + hh * WD;
            #pragma unroll
            for (int it = 0; it < 4; ++it) {
                int p = it * 32 + (tid & 31);
                uintx4 pv;
                #pragma unroll
                for (int cc = 0; cc < 4; ++cc) {
                    float a  = xg[(size_t)(2 * cc) * HWSZ + p];
                    float b2 = xg[(size_t)(2 * cc + 1) * HWSZ + p];
                    pv[cc] = pack2bf(a, b2);
                }
                *(uintx4*)&lds.xl[(p + 1) * XSTR + g * 8] = pv;
            }
        }

        __syncthreads();

        // ---- 3 dw taps share this staging; W fragments direct from global wp
        // (73.7 KB table, L1/L2-hot, shared by all blocks). Named regs only.
        #pragma unroll
        for (int dw = 0; dw < 3; ++dw) {
            const int k = dh * 3 + dw;
            #pragma unroll
            for (int ks = 0; ks < 2; ++ks) {
                short8 bv0, bv1, bv2, bv3;
                if (wp) {
                    const unsigned short* wk = wp + k * 4096 + ks * 32 + q * 8;
                    bv0 = *(const short8*)&wk[(0 * 16 + row) * 64];
                    bv1 = *(const short8*)&wk[(1 * 16 + row) * 64];
                    bv2 = *(const short8*)&wk[(2 * 16 + row) * 64];
                    bv3 = *(const short8*)&wk[(3 * 16 + row) * 64];
                } else {
                    #pragma unroll
                    for (int j = 0; j < 8; ++j) {
                        int c = ks * 32 + q * 8 + j;
                        bv0[j] = f2bf(2.0f * wgt[(0*16+row) * 576 + c * 9 + k]);
                        bv1[j] = f2bf(2.0f * wgt[(1*16+row) * 576 + c * 9 + k]);
                        bv2[j] = f2bf(2.0f * wgt[(2*16+row) * 576 + c * 9 + k]);
                        bv3[j] = f2bf(2.0f * wgt[(3*16+row) * 576 + c * 9 + k]);
                    }
                }

                short8 af[2];
                #pragma unroll
                for (int mt = 0; mt < 2; ++mt) {
                    int wslot = (mt0 + mt) * 16 + row + dw;   // = p + dw, xl slot of w=p+dw-1
                    short8 raw = *(const short8*)&lds.xl[wslot * XSTR + ks * 32 + q * 8];
                    float es = esv[k][mt];
                    #pragma unroll
                    for (int jj = 0; jj < 4; ++jj) {
                        float d0 = fmaf(eg[mt][ks][2 * jj],     es, 1.0f);
                        float d1 = fmaf(eg[mt][ks][2 * jj + 1], es, 1.0f);
                        float r0 = __builtin_amdgcn_rcpf(d0);
                        float r1 = __builtin_amdgcn_rcpf(d1);
                        float x0 = bf2f(raw[2 * jj]);
                        float x1 = bf2f(raw[2 * jj + 1]);
                        float t0 = fmaf(-x0, r0, x0);   // x * u/(1+u); the 2 lives in w
                        float t1 = fmaf(-x1, r1, x1);
                        ((unsigned*)&af[mt])[jj] = pack2bf(t0, t1);
                    }
                }
                acc[0][0] = __builtin_amdgcn_mfma_f32_16x16x32_bf16(af[0], bv0, acc[0][0], 0, 0, 0);
                acc[1][0] = __builtin_amdgcn_mfma_f32_16x16x32_bf16(af[1], bv0, acc[1][0], 0, 0, 0);
                acc[0][1] = __builtin_amdgcn_mfma_f32_16x16x32_bf16(af[0], bv1, acc[0][1], 0, 0, 0);
                acc[1][1] = __builtin_amdgcn_mfma_f32_16x16x32_bf16(af[1], bv1, acc[1][1], 0, 0, 0);
                acc[0][2] = __builtin_amdgcn_mfma_f32_16x16x32_bf16(af[0], bv2, acc[0][2], 0, 0, 0);
                acc[1][2] = __builtin_amdgcn_mfma_f32_16x16x32_bf16(af[1], bv2, acc[1][2], 0, 0, 0);
                acc[0][3] = __builtin_amdgcn_mfma_f32_16x16x32_bf16(af[0], bv3, acc[0][3], 0, 0, 0);
                acc[1][3] = __builtin_amdgcn_mfma_f32_16x16x32_bf16(af[1], bv3, acc[1][3], 0, 0, 0);
            }
        }
    }

    __syncthreads();

    // D layout: col(=o) = lane&15, rowD(=p) = (lane>>4)*4 + reg.
    // b128 transpose writes: granule = 2*row + q (mod 32) -> <=2-way = free.
    #pragma unroll
    for (int i = 0; i < 2; ++i) {
        int prow = (mt0 + i) * 16 + q * 4;
        #pragma unroll
        for (int nt = 0; nt < 4; ++nt) {
            int o = nt * 16 + row;
            *(floatx4*)&lds.o[o * OSTR + prow] = acc[i][nt];
        }
    }

    __syncthreads();

    // coalesced float4 stores: out[b][o][h][0..127]; read granule 2o+j -> 2-way = free
    float* outb = out + ((size_t)b * OD) * HWSZ + h * WD;
    #pragma unroll
    for (int it = 0; it < 8; ++it) {
        int idx = it * 256 + tid;              // 2048 float4s
        int o = idx >> 5, p4 = (idx & 31) * 4;
        *(floatx4*)&outb[(size_t)o * HWSZ + p4] = *(const floatx4*)&lds.o[o * OSTR + p4];
    }
}

extern "C" void kernel_launch(void* const* d_in, const int* in_sizes, int n_in,
                              void* d_out, int out_size, void* d_ws, size_t ws_size,
                              hipStream_t stream) {
    const float* x   = (const float*)d_in[0];
    const float* gcp = (const float*)d_in[1];
    const float* gsp = (const float*)d_in[2];
    const float* wgt = (const float*)d_in[3];
    float* out = (float*)d_out;

    const bool use_wp = ws_size >= (size_t)(9 * 64 * 64 * sizeof(unsigned short));
    unsigned short* wp = use_wp ? (unsigned short*)d_ws : nullptr;
    if (use_wp)
        prepack_w<<<dim3(144), dim3(256), 0, stream>>>(wgt, wp);
    paka_kernel<<<dim3(1024), dim3(256), 0, stream>>>(x, gcp, gsp, wgt, wp, out);
}